// Round 19
// baseline (452.982 us; speedup 1.0000x reference)
//
#include <hip/hip_runtime.h>

// ConvLSTM2D MI355X, R19: R17 body exactly (176us anchor; R18's two tweaks
// reverted — both neutral/negative), + FULL unroll of the 9-chunk X and
// 18-chunk H loops. With tap/c compile-time: koff div/mod vanishes, LDS reads
// become base+offset:N immediates, weight pointers become constant strides,
// and the compiler schedules global weight loads across the whole phase
// (~200cyc L2 latency hidden). Weight bases hoisted above the t-loop.
// 512 blocks x 256 thr (2 independent blocks/CU), local 8-neighbor sync,
// h interior in LDS, ring via sc0sc1, c in registers, X-before-poll.

typedef __attribute__((ext_vector_type(8))) short short8v;
typedef __attribute__((ext_vector_type(4))) float f32x4;
typedef __attribute__((ext_vector_type(4))) unsigned int u32x4;
typedef unsigned short u16;

#define HS 808             // shorts per kb block in H halo (101 x 16B slots)
#define HB 3200            // H halo base (shorts); X halo = [0, 3200)

__device__ __forceinline__ u16 f2bf(float x) {
    union { float f; unsigned u; } a; a.f = x;
    unsigned r = a.u + 0x7FFFu + ((a.u >> 16) & 1u);   // RNE
    return (u16)(r >> 16);
}
__device__ __forceinline__ float sigf(float x) { return 1.0f / (1.0f + __expf(-x)); }
__device__ __forceinline__ float tanhf_(float x) {
    float e = __expf(2.0f * x);
    return 1.0f - 2.0f / (e + 1.0f);
}

// ---- prep: x f32 -> bf16 ----
__global__ __launch_bounds__(256)
void prep_x(const float* __restrict__ x, u16* __restrict__ xb) {
    size_t i = (size_t)blockIdx.x * 256 + threadIdx.x;
    for (; i < 2621440u; i += (size_t)2048 * 256) {
        float4 v = ((const float4*)x)[i];
        union { u16 u[4]; uint2 q; } o;
        o.u[0] = f2bf(v.x); o.u[1] = f2bf(v.y);
        o.u[2] = f2bf(v.z); o.u[3] = f2bf(v.w);
        ((uint2*)xb)[i] = o.q;
    }
}

// ---- prep: weights -> staged layout + zero flags ----
__global__ __launch_bounds__(256)
void prep_w(const float* __restrict__ kern, const float* __restrict__ rk,
            u16* __restrict__ wt_in, u16* __restrict__ wt_rk,
            unsigned* __restrict__ flags) {
    int idx = blockIdx.x * 256 + threadIdx.x;
    if (idx < 512) flags[idx] = 0u;
    if (idx >= 82944) return;
    const float* s;
    u16* dst;
    if (idx < 9216) {
        int co = idx & 255, ckb = idx >> 8;          // 0..35 = tap*4+kb
        int tap = ckb >> 2, kb = ckb & 3;
        s = kern + (size_t)((tap << 5) + (kb << 3)) * 256 + co;
        dst = wt_in + (size_t)idx * 8;
    } else {
        int j = idx - 9216;
        int co = j & 255, rest = j >> 8;             // 0..287
        int kb = rest & 3, gc = rest >> 2;           // gc = g*18 + cc
        int g = gc / 18, cc = gc - g * 18;
        int tap = cc >> 1;
        int cib = (cc & 1) << 5;
        s = rk + (size_t)(((g * 9 + tap) << 6) + cib + (kb << 3)) * 256 + co;
        dst = wt_rk + (size_t)j * 8;
    }
    union { u16 u[8]; uint4 q; } o;
    #pragma unroll
    for (int i = 0; i < 8; ++i) o.u[i] = f2bf(s[i * 256]);
    *(uint4*)dst = o.q;
}

__device__ __forceinline__ void stageX(const u16* __restrict__ src,
                                       short* __restrict__ halX,
                                       int tid, int y0, int x0) {
    #pragma unroll 2
    for (int s = tid; s < 400; s += 256) {
        int pos = s >> 2, kb = s & 3;
        int hy = pos / 10, hx = pos - hy * 10;
        int gy = y0 + hy - 1, gx = x0 + hx - 1;
        short8v v = (short8v){0,0,0,0,0,0,0,0};
        if ((unsigned)gy < 64u && (unsigned)gx < 64u)
            v = *(const short8v*)&src[(((gy << 6) + gx) << 5) + (kb << 3)];
        *(short8v*)&halX[kb * 800 + pos * 8] = v;
    }
}

// ---- persistent fused conv + gates, all timesteps ----
__global__ __launch_bounds__(256, 2)
void lstm_all(const u16* __restrict__ xb,     // (8,10,64,64,32) bf16
              const u16* __restrict__ wt_in, const u16* __restrict__ wt_rk,
              const float* __restrict__ bias, const int* __restrict__ labels,
              u16* __restrict__ hb0, u16* __restrict__ hb1,  // h ring bufs
              float* __restrict__ out, unsigned* __restrict__ flags)
{
    // X halo @0: [kb4][100][8] (3200 shorts); H halo @3200: [kb8][HS=808]
    __shared__ short hal[HB + 8 * HS];   // 9664 shorts = 19,328 B

    const int tid  = threadIdx.x;
    const int lane = tid & 63;
    const int wq   = tid >> 6;                 // wave = f-slice 0..3
    const int b    = blockIdx.x >> 6;
    const int tile = blockIdx.x & 63;
    const int ty = tile >> 3, tx = tile & 7;
    const int y0 = ty << 3, x0 = tx << 3;
    const int g = labels[b];

    const int co_l = lane & 15;
    const int kbl  = lane >> 4;
    const int prow = (lane & 15) >> 3, pcol = lane & 7;
    const int f = (wq << 4) + co_l;

    float bv[4];
    #pragma unroll
    for (int n = 0; n < 4; ++n)
        bv[n] = bias[(g << 8) + (n << 6) + f];

    // hoisted weight bases (per-thread constants; chunk offset = c * 8192)
    const u16* wbx0 = wt_in + (size_t)((kbl << 8) + f) * 8;
    const u16* wbh0 = wt_rk + (size_t)(((((g * 18) << 2) + kbl) << 8) + f) * 8;

    int aoffm[4];
    #pragma unroll
    for (int m = 0; m < 4; ++m)
        aoffm[m] = ((m << 1) + prow) * 10 + pcol;

    int poff[4][4], loff[4][4];
    #pragma unroll
    for (int m = 0; m < 4; ++m)
        #pragma unroll
        for (int rr = 0; rr < 4; ++rr) {
            int pf = (kbl << 2) + rr;
            int ly = (m << 1) + (pf >> 3);
            int lx = pf & 7;
            poff[m][rr] = ((((y0 + ly) << 6) + x0 + lx) << 6) + f;
            loff[m][rr] = HB + (f >> 3) * HS + ((ly + 1) * 10 + lx + 1) * 8 + (f & 7);
        }

    float cst[4][4];
    #pragma unroll
    for (int m = 0; m < 4; ++m)
        #pragma unroll
        for (int rr = 0; rr < 4; ++rr) cst[m][rr] = 0.0f;

    const u16* xsrc = xb + ((size_t)b * 10 << 17);
    float*     ob0  = out + ((size_t)b * 10 << 18);
    unsigned*  myfl = flags + (b << 6) + tile;

    // zero H halo (out-of-image ring cells stay 0 forever); stage X(0)
    for (int s = tid; s < 808; s += 256)
        *(short8v*)&hal[HB + s * 8] = (short8v){0,0,0,0,0,0,0,0};
    stageX(xsrc, hal, tid, y0, x0);
    __syncthreads();

    for (int t = 0; t < 10; ++t) {
        u16* hw = ((t & 1) ? hb1 : hb0) + ((size_t)b << 18);   // h(t)

        f32x4 acc[4][4];
        #pragma unroll
        for (int n = 0; n < 4; ++n)
            #pragma unroll
            for (int m = 0; m < 4; ++m)
                acc[m][n] = (f32x4){bv[n], bv[n], bv[n], bv[n]};

        // ---- phase X: 9 chunks, FULLY unrolled (koff/offsets compile-time) ----
        #pragma unroll
        for (int tap = 0; tap < 9; ++tap) {
            const int koff = (tap / 3) * 10 + (tap % 3);
            const u16* wb = wbx0 + (size_t)tap * 8192;
            short8v bfr[4], af[4];
            #pragma unroll
            for (int n = 0; n < 4; ++n)
                bfr[n] = *(const short8v*)&wb[(size_t)n << 9];
            #pragma unroll
            for (int m = 0; m < 4; ++m)
                af[m] = *(const short8v*)&hal[kbl * 800 + (aoffm[m] + koff) * 8];
            #pragma unroll
            for (int m = 0; m < 4; ++m)
                #pragma unroll
                for (int n = 0; n < 4; ++n)
                    acc[m][n] = __builtin_amdgcn_mfma_f32_16x16x32_bf16(af[m], bfr[n], acc[m][n], 0, 0, 0);
        }

        if (t > 0) {
            // ---- poll 8 neighbor flags (wave 0): need h(t-1) exported ----
            if (tid < 64) {
                bool valid = false; int fidx = 0;
                if (tid < 8) {
                    int kk = tid + (tid >= 4);       // 0..8 skipping center
                    int nty = ty + kk / 3 - 1, ntx = tx + kk % 3 - 1;
                    valid = (unsigned)nty < 8u && (unsigned)ntx < 8u;
                    fidx = (b << 6) + (nty << 3) + ntx;
                }
                unsigned tgt = (unsigned)t;
                int guard = 0;
                for (;;) {
                    unsigned vv = tgt;
                    if (valid)
                        vv = __hip_atomic_load(flags + fidx, __ATOMIC_RELAXED,
                                               __HIP_MEMORY_SCOPE_SYSTEM);
                    if (__all(vv >= tgt)) break;
                    if (++guard > (1 << 19)) break;
                    __builtin_amdgcn_s_sleep(2);
                }
            }
            __syncthreads();   // neighbors' h(t-1) rings globally visible

            // ---- import ring h(t-1): 36 px x 8 units, sc0sc1 16B ----
            {
                const u16* hr = ((t & 1) ? hb0 : hb1) + ((size_t)b << 18);
                #pragma unroll
                for (int u = 0; u < 2; ++u) {
                    int s = tid + (u << 8);
                    if (s < 288) {
                        int posr = s >> 3, kb = s & 7;
                        int hy, hx;
                        if (posr < 10)      { hy = 0; hx = posr; }
                        else if (posr < 20) { hy = 9; hx = posr - 10; }
                        else { int v = posr - 20; hy = 1 + (v >> 1); hx = (v & 1) * 9; }
                        int gy = y0 + hy - 1, gx = x0 + hx - 1;
                        bool inb = (unsigned)gy < 64u && (unsigned)gx < 64u;
                        const u16* ga = inb ? (hr + (((gy << 6) + gx) << 6) + (kb << 3)) : hr;
                        u32x4 v;
                        asm volatile("global_load_dwordx4 %0, %1, off sc0 sc1"
                                     : "=v"(v) : "v"(ga) : "memory");
                        asm volatile("s_waitcnt vmcnt(0)" ::: "memory");
                        __builtin_amdgcn_sched_barrier(0);
                        if (!inb) v = (u32x4){0u, 0u, 0u, 0u};
                        *(u32x4*)&hal[HB + kb * HS + (hy * 10 + hx) * 8] = v;
                    }
                }
            }
            __syncthreads();   // ring in LDS

            // ---- phase H: 18 chunks, FULLY unrolled ----
            #pragma unroll
            for (int c = 0; c < 18; ++c) {
                const int tap = c >> 1;
                const int koff = (tap / 3) * 10 + (tap % 3);
                const u16* wb = wbh0 + (size_t)c * 8192;
                short8v bfr[4], af[4];
                #pragma unroll
                for (int n = 0; n < 4; ++n)
                    bfr[n] = *(const short8v*)&wb[(size_t)n << 9];
                const int abase = HB + (((c & 1) << 2) + kbl) * HS;
                #pragma unroll
                for (int m = 0; m < 4; ++m)
                    af[m] = *(const short8v*)&hal[abase + (aoffm[m] + koff) * 8];
                #pragma unroll
                for (int m = 0; m < 4; ++m)
                    #pragma unroll
                    for (int n = 0; n < 4; ++n)
                        acc[m][n] = __builtin_amdgcn_mfma_f32_16x16x32_bf16(af[m], bfr[n], acc[m][n], 0, 0, 0);
            }
        }
        __syncthreads();   // sync1: H-LDS (h(t-1)) reads complete

        // ---- gates + out store + h(t) interior -> LDS ----
        float* ob = ob0 + ((size_t)t << 18);
        #pragma unroll
        for (int m = 0; m < 4; ++m) {
            #pragma unroll
            for (int rr = 0; rr < 4; ++rr) {
                float zi = acc[m][0][rr], zf = acc[m][1][rr];
                float zg = acc[m][2][rr], zo = acc[m][3][rr];
                float cn = sigf(zf) * cst[m][rr] + sigf(zi) * tanhf_(zg);
                float hn = sigf(zo) * tanhf_(cn);
                cst[m][rr] = cn;
                ob[poff[m][rr]] = hn;
                hal[loff[m][rr]] = (short)f2bf(hn);
            }
        }
        __syncthreads();   // sync2: interior h(t) in LDS

        if (t < 9) {
            // ---- ring export: 28 boundary px x 8 units, sc0sc1 16B ----
            if (tid < 224) {
                int pxr = tid >> 3, kb = tid & 7;
                int dy, dx;
                if (pxr < 8)       { dy = 0; dx = pxr; }
                else if (pxr < 16) { dy = 7; dx = pxr - 8; }
                else { int v = pxr - 16; dy = 1 + (v >> 1); dx = (v & 1) * 7; }
                u32x4 v = *(const u32x4*)&hal[HB + kb * HS + ((dy + 1) * 10 + dx + 1) * 8];
                const u16* ga = hw + ((((y0 + dy) << 6) + x0 + dx) << 6) + (kb << 3);
                asm volatile("global_store_dwordx4 %0, %1, off sc0 sc1"
                             :: "v"(ga), "v"(v) : "memory");
            }
            // ---- stage X(t+1) (overlaps export latency) ----
            stageX(xsrc + ((size_t)(t + 1) << 17), hal, tid, y0, x0);
            asm volatile("s_waitcnt vmcnt(0)" ::: "memory");  // exports drained
            __syncthreads();   // sync3: exports + X(t+1) staged
            if (tid == 0)
                __hip_atomic_fetch_add(myfl, 1u, __ATOMIC_RELAXED,
                                       __HIP_MEMORY_SCOPE_SYSTEM);
        }
    }
}

extern "C" void kernel_launch(void* const* d_in, const int* in_sizes, int n_in,
                              void* d_out, int out_size, void* d_ws, size_t ws_size,
                              hipStream_t stream)
{
    const float* x    = (const float*)d_in[0];
    const int*   lbl  = (const int*)  d_in[1];
    const float* kern = (const float*)d_in[2];
    const float* rk   = (const float*)d_in[3];
    const float* bias = (const float*)d_in[4];
    float* out = (float*)d_out;

    // ws: xb 20.97MB | hb0 4.19 | hb1 4.19 | wt_in 0.147 | wt_rk 1.18 | flags 2KB
    u16* xb    = (u16*)d_ws;
    u16* hb0   = xb + 10485760;
    u16* hb1   = hb0 + 2097152;
    u16* wt_in = hb1 + 2097152;
    u16* wt_rk = wt_in + 73728;
    unsigned* flags = (unsigned*)(wt_rk + 589824);

    hipLaunchKernelGGL(prep_x, dim3(2048), dim3(256), 0, stream, x, xb);
    hipLaunchKernelGGL(prep_w, dim3(324), dim3(256), 0, stream,
                       kern, rk, wt_in, wt_rk, flags);

    // Regular launch; co-residency guaranteed by __launch_bounds__(256, 2)
    // capacity (2 blocks/CU x 256 CUs = 512 blocks exactly; guide §1).
    hipLaunchKernelGGL(lstm_all, dim3(512), dim3(256), 0, stream,
                       xb, wt_in, wt_rk, bias, lbl, hb0, hb1, out, flags);
}

// Round 20
// 241.452 us; speedup vs baseline: 1.8761x; 1.8761x over previous
//
#include <hip/hip_runtime.h>

// ConvLSTM2D MI355X, R20: R17 skeleton (176us anchor: 512 blk x 256 thr,
// 2 independent blocks/CU, local 8-neighbor sync, sc0sc1 ring, c in regs)
// with the conv engine moved from 16x16x32 (432 mfma/wave) to 32x32x16
// (216 mfma/wave, -17% mfma cycles, half the instruction count).
// TRANSPOSED product: D[co][px] = W x Act. C/D (verified m74/m101):
// col=lane&31 (px), row=(reg&3)+8*(reg>>2)+4*(lane>>5) (co-row). With
// co-row r -> gate=r>>3, fsub=r&7, each lane's reg block holds all 4 gates
// of its (px,f): reg = gate*4+q. A/B operand layout by analogy with the
// m89-verified 16x16x32 pattern: row/col=lane&31, k=(lane>>5)*8+i.
// Bias added in epilogue (float4 L1 loads) to save VGPR.

typedef __attribute__((ext_vector_type(8))) short short8v;
typedef __attribute__((ext_vector_type(16))) float f32x16;
typedef __attribute__((ext_vector_type(4))) unsigned int u32x4;
typedef unsigned short u16;

#define HS 808             // shorts per kb block in H halo (101 x 16B slots)
#define HB 3200            // H halo base (shorts); X halo = [0, 3200)

__device__ __forceinline__ u16 f2bf(float x) {
    union { float f; unsigned u; } a; a.f = x;
    unsigned r = a.u + 0x7FFFu + ((a.u >> 16) & 1u);   // RNE
    return (u16)(r >> 16);
}
__device__ __forceinline__ float sigf(float x) { return 1.0f / (1.0f + __expf(-x)); }
__device__ __forceinline__ float tanhf_(float x) {
    float e = __expf(2.0f * x);
    return 1.0f - 2.0f / (e + 1.0f);
}

// ---- prep: x f32 -> bf16 ----
__global__ __launch_bounds__(256)
void prep_x(const float* __restrict__ x, u16* __restrict__ xb) {
    size_t i = (size_t)blockIdx.x * 256 + threadIdx.x;
    for (; i < 2621440u; i += (size_t)2048 * 256) {
        float4 v = ((const float4*)x)[i];
        union { u16 u[4]; uint2 q; } o;
        o.u[0] = f2bf(v.x); o.u[1] = f2bf(v.y);
        o.u[2] = f2bf(v.z); o.u[3] = f2bf(v.w);
        ((uint2*)xb)[i] = o.q;
    }
}

// ---- prep: weights -> 32x32x16 A-operand layout + zero flags ----
// wt_in[s18][wq4][mt2][kq2][r32][8i]: tap=s>>1, kh=s&1; ci = kh*16+kq*8+i;
// co = (r>>3)*64 + wq*16 + mt*8 + (r&7).
// wt_rk[g4][s36][wq4][mt2][kq2][r32][8i]: tap=s>>2, kh4=s&3; hch=kh4*16+kq*8+i.
__global__ __launch_bounds__(256)
void prep_w(const float* __restrict__ kern, const float* __restrict__ rk,
            u16* __restrict__ wt_in, u16* __restrict__ wt_rk,
            unsigned* __restrict__ flags) {
    int idx = blockIdx.x * 256 + threadIdx.x;
    if (idx < 512) flags[idx] = 0u;
    if (idx >= 82944) return;
    const float* s_;
    u16* dst;
    if (idx < 9216) {
        int r  = idx & 31;
        int t1 = idx >> 5;
        int kq = t1 & 1;
        int t2 = t1 >> 1;
        int mt = t2 & 1;
        int t3 = t2 >> 1;
        int wqi = t3 & 3;
        int s  = t3 >> 2;                    // 0..17
        int tap = s >> 1, kh = s & 1;
        int co = ((r >> 3) << 6) + (wqi << 4) + (mt << 3) + (r & 7);
        int ci0 = (kh << 4) + (kq << 3);
        s_ = kern + (size_t)((tap << 5) + ci0) * 256 + co;
        dst = wt_in + (size_t)idx * 8;
    } else {
        int j = idx - 9216;
        int r  = j & 31;
        int t1 = j >> 5;
        int kq = t1 & 1;
        int t2 = t1 >> 1;
        int mt = t2 & 1;
        int t3 = t2 >> 1;
        int wqi = t3 & 3;
        int t4 = t3 >> 2;                    // 0..143
        int g = t4 / 36, s = t4 - g * 36;
        int tap = s >> 2, kh4 = s & 3;
        int co = ((r >> 3) << 6) + (wqi << 4) + (mt << 3) + (r & 7);
        int h0 = (kh4 << 4) + (kq << 3);
        s_ = rk + (size_t)(((g * 9 + tap) << 6) + h0) * 256 + co;
        dst = wt_rk + (size_t)j * 8;
    }
    union { u16 u[8]; uint4 q; } o;
    #pragma unroll
    for (int i = 0; i < 8; ++i) o.u[i] = f2bf(s_[i * 256]);
    *(uint4*)dst = o.q;
}

__device__ __forceinline__ void stageX(const u16* __restrict__ src,
                                       short* __restrict__ halX,
                                       int tid, int y0, int x0) {
    #pragma unroll 2
    for (int s = tid; s < 400; s += 256) {
        int pos = s >> 2, kb = s & 3;
        int hy = pos / 10, hx = pos - hy * 10;
        int gy = y0 + hy - 1, gx = x0 + hx - 1;
        short8v v = (short8v){0,0,0,0,0,0,0,0};
        if ((unsigned)gy < 64u && (unsigned)gx < 64u)
            v = *(const short8v*)&src[(((gy << 6) + gx) << 5) + (kb << 3)];
        *(short8v*)&halX[kb * 800 + pos * 8] = v;
    }
}

// ---- persistent fused conv + gates, all timesteps ----
__global__ __launch_bounds__(256, 2)
void lstm_all(const u16* __restrict__ xb,     // (8,10,64,64,32) bf16
              const u16* __restrict__ wt_in, const u16* __restrict__ wt_rk,
              const float* __restrict__ bias, const int* __restrict__ labels,
              u16* __restrict__ hb0, u16* __restrict__ hb1,  // h ring bufs
              float* __restrict__ out, unsigned* __restrict__ flags)
{
    // X halo @0: [kb4][100][8] (3200 shorts); H halo @3200: [kb8][HS=808]
    __shared__ short hal[HB + 8 * HS];   // 9664 shorts = 19,328 B

    const int tid  = threadIdx.x;
    const int lane = tid & 63;
    const int wq   = tid >> 6;                 // wave = f-slice of 16
    const int b    = blockIdx.x >> 6;
    const int tile = blockIdx.x & 63;
    const int ty = tile >> 3, tx = tile & 7;
    const int y0 = ty << 3, x0 = tx << 3;
    const int g = labels[b];

    const int l31 = lane & 31;
    const int kqv = lane >> 5;                 // k-half / hi selector

    // per-nt pixel geometry: px = nt*32 + l31
    int aoffn[2], pxoff[2];
    #pragma unroll
    for (int nt = 0; nt < 2; ++nt) {
        int px = (nt << 5) + l31;
        int py = px >> 3, pxx = px & 7;
        aoffn[nt] = py * 10 + pxx;             // conv window base in halo
        pxoff[nt] = ((((y0 + py) << 6) + x0 + pxx) << 6);
    }

    // A-operand (weights) per-lane bases
    const u16* wax = wt_in + (size_t)((wq << 10) + (kqv << 8) + (l31 << 3));
    const u16* wah = wt_rk + (size_t)g * 147456 + (wq << 10) + (kqv << 8) + (l31 << 3);

    const float* bb = bias + (g << 8);

    float cst[2][2][4];
    #pragma unroll
    for (int mt = 0; mt < 2; ++mt)
        #pragma unroll
        for (int nt = 0; nt < 2; ++nt)
            #pragma unroll
            for (int q = 0; q < 4; ++q) cst[mt][nt][q] = 0.0f;

    const u16* xsrc = xb + ((size_t)b * 10 << 17);
    float*     ob0  = out + ((size_t)b * 10 << 18);
    unsigned*  myfl = flags + (b << 6) + tile;

    // zero H halo (out-of-image ring cells stay 0 forever); stage X(0)
    for (int s = tid; s < 808; s += 256)
        *(short8v*)&hal[HB + s * 8] = (short8v){0,0,0,0,0,0,0,0};
    stageX(xsrc, hal, tid, y0, x0);
    __syncthreads();

    for (int t = 0; t < 10; ++t) {
        u16* hw = ((t & 1) ? hb1 : hb0) + ((size_t)b << 18);   // h(t)

        f32x16 acc[2][2];
        #pragma unroll
        for (int mt = 0; mt < 2; ++mt)
            #pragma unroll
            for (int nt = 0; nt < 2; ++nt)
                acc[mt][nt] = (f32x16){};      // zero; bias in epilogue

        // ---- phase X: 9 taps x 2 k-halves (K=16 each) ----
        #pragma unroll 1
        for (int tap = 0; tap < 9; ++tap) {
            const int koff = (tap / 3) * 10 + (tap % 3);
            #pragma unroll
            for (int kh = 0; kh < 2; ++kh) {
                const int s = tap * 2 + kh;
                short8v a0 = *(const short8v*)&wax[(size_t)s * 4096];
                short8v a1 = *(const short8v*)&wax[(size_t)s * 4096 + 512];
                const int kb = (kh << 1) + kqv;
                short8v b0 = *(const short8v*)&hal[kb * 800 + (aoffn[0] + koff) * 8];
                short8v b1 = *(const short8v*)&hal[kb * 800 + (aoffn[1] + koff) * 8];
                acc[0][0] = __builtin_amdgcn_mfma_f32_32x32x16_bf16(a0, b0, acc[0][0], 0, 0, 0);
                acc[0][1] = __builtin_amdgcn_mfma_f32_32x32x16_bf16(a0, b1, acc[0][1], 0, 0, 0);
                acc[1][0] = __builtin_amdgcn_mfma_f32_32x32x16_bf16(a1, b0, acc[1][0], 0, 0, 0);
                acc[1][1] = __builtin_amdgcn_mfma_f32_32x32x16_bf16(a1, b1, acc[1][1], 0, 0, 0);
            }
        }

        if (t > 0) {
            // ---- poll 8 neighbor flags (wave 0): need h(t-1) exported ----
            if (tid < 64) {
                bool valid = false; int fidx = 0;
                if (tid < 8) {
                    int kk = tid + (tid >= 4);       // 0..8 skipping center
                    int nty = ty + kk / 3 - 1, ntx = tx + kk % 3 - 1;
                    valid = (unsigned)nty < 8u && (unsigned)ntx < 8u;
                    fidx = (b << 6) + (nty << 3) + ntx;
                }
                unsigned tgt = (unsigned)t;
                int guard = 0;
                for (;;) {
                    unsigned vv = tgt;
                    if (valid)
                        vv = __hip_atomic_load(flags + fidx, __ATOMIC_RELAXED,
                                               __HIP_MEMORY_SCOPE_SYSTEM);
                    if (__all(vv >= tgt)) break;
                    if (++guard > (1 << 19)) break;
                    __builtin_amdgcn_s_sleep(2);
                }
            }
            __syncthreads();   // neighbors' h(t-1) rings globally visible

            // ---- import ring h(t-1): 36 px x 8 units, sc0sc1 16B ----
            {
                const u16* hr = ((t & 1) ? hb0 : hb1) + ((size_t)b << 18);
                #pragma unroll
                for (int u = 0; u < 2; ++u) {
                    int s = tid + (u << 8);
                    if (s < 288) {
                        int posr = s >> 3, kb = s & 7;
                        int hy, hx;
                        if (posr < 10)      { hy = 0; hx = posr; }
                        else if (posr < 20) { hy = 9; hx = posr - 10; }
                        else { int v = posr - 20; hy = 1 + (v >> 1); hx = (v & 1) * 9; }
                        int gy = y0 + hy - 1, gx = x0 + hx - 1;
                        bool inb = (unsigned)gy < 64u && (unsigned)gx < 64u;
                        const u16* ga = inb ? (hr + (((gy << 6) + gx) << 6) + (kb << 3)) : hr;
                        u32x4 v;
                        asm volatile("global_load_dwordx4 %0, %1, off sc0 sc1"
                                     : "=v"(v) : "v"(ga) : "memory");
                        asm volatile("s_waitcnt vmcnt(0)" ::: "memory");
                        __builtin_amdgcn_sched_barrier(0);
                        if (!inb) v = (u32x4){0u, 0u, 0u, 0u};
                        *(u32x4*)&hal[HB + kb * HS + (hy * 10 + hx) * 8] = v;
                    }
                }
            }
            __syncthreads();   // ring in LDS

            // ---- phase H: 9 taps x 4 k-quarters (K=16 each) ----
            #pragma unroll 1
            for (int tap = 0; tap < 9; ++tap) {
                const int koff = (tap / 3) * 10 + (tap % 3);
                #pragma unroll 2
                for (int kh4 = 0; kh4 < 4; ++kh4) {
                    const int s = tap * 4 + kh4;
                    short8v a0 = *(const short8v*)&wah[(size_t)s * 4096];
                    short8v a1 = *(const short8v*)&wah[(size_t)s * 4096 + 512];
                    const int kb = (kh4 << 1) + kqv;
                    short8v b0 = *(const short8v*)&hal[HB + kb * HS + (aoffn[0] + koff) * 8];
                    short8v b1 = *(const short8v*)&hal[HB + kb * HS + (aoffn[1] + koff) * 8];
                    acc[0][0] = __builtin_amdgcn_mfma_f32_32x32x16_bf16(a0, b0, acc[0][0], 0, 0, 0);
                    acc[0][1] = __builtin_amdgcn_mfma_f32_32x32x16_bf16(a0, b1, acc[0][1], 0, 0, 0);
                    acc[1][0] = __builtin_amdgcn_mfma_f32_32x32x16_bf16(a1, b0, acc[1][0], 0, 0, 0);
                    acc[1][1] = __builtin_amdgcn_mfma_f32_32x32x16_bf16(a1, b1, acc[1][1], 0, 0, 0);
                }
            }
        }
        __syncthreads();   // sync1: H-LDS (h(t-1)) reads complete

        // ---- gates + out store + h(t) interior -> LDS ----
        // reg r = gate*4 + q; row=(r&3)+8*(r>>2)+4*kqv -> gate=r>>2? NO:
        // row=(r&3)+8*(r>>2)+4*kqv; for fixed rr=r>>2: rows 8*rr+4*kqv+[0,4)
        // -> gate=(row>>3)=rr? row=8*rr+4kqv+q03: row>>3 = rr (q+4kqv<8) ✓
        // so gate = r>>2, fsub = (r&3) + 4*kqv. f = wq*16 + mt*8 + fsub.
        float* ob = ob0 + ((size_t)t << 18);
        #pragma unroll
        for (int mt = 0; mt < 2; ++mt) {
            const int fb = (wq << 4) + (mt << 3) + (kqv << 2);   // f base (q adds)
            float4 bi = *(const float4*)&bb[fb];
            float4 bf4 = *(const float4*)&bb[64 + fb];
            float4 bg4 = *(const float4*)&bb[128 + fb];
            float4 bo4 = *(const float4*)&bb[192 + fb];
            #pragma unroll
            for (int nt = 0; nt < 2; ++nt) {
                #pragma unroll
                for (int q = 0; q < 4; ++q) {
                    float zi = acc[mt][nt][q]      + ((const float*)&bi)[q];
                    float zf = acc[mt][nt][4 + q]  + ((const float*)&bf4)[q];
                    float zg = acc[mt][nt][8 + q]  + ((const float*)&bg4)[q];
                    float zo = acc[mt][nt][12 + q] + ((const float*)&bo4)[q];
                    float cn = sigf(zf) * cst[mt][nt][q] + sigf(zi) * tanhf_(zg);
                    float hn = sigf(zo) * tanhf_(cn);
                    cst[mt][nt][q] = cn;
                    int f = fb + q;
                    ob[pxoff[nt] + f] = hn;
                    hal[HB + ((wq << 1) + mt) * HS + (aoffn[nt] + 11) * 8 + (f & 7)]
                        = (short)f2bf(hn);
                }
            }
        }
        __syncthreads();   // sync2: interior h(t) in LDS

        if (t < 9) {
            // ---- ring export: 28 boundary px x 8 units, sc0sc1 16B ----
            if (tid < 224) {
                int pxr = tid >> 3, kb = tid & 7;
                int dy, dx;
                if (pxr < 8)       { dy = 0; dx = pxr; }
                else if (pxr < 16) { dy = 7; dx = pxr - 8; }
                else { int v = pxr - 16; dy = 1 + (v >> 1); dx = (v & 1) * 7; }
                u32x4 v = *(const u32x4*)&hal[HB + kb * HS + ((dy + 1) * 10 + dx + 1) * 8];
                const u16* ga = hw + ((((y0 + dy) << 6) + x0 + dx) << 6) + (kb << 3);
                asm volatile("global_store_dwordx4 %0, %1, off sc0 sc1"
                             :: "v"(ga), "v"(v) : "memory");
            }
            // ---- stage X(t+1) (overlaps export latency) ----
            stageX(xsrc + ((size_t)(t + 1) << 17), hal, tid, y0, x0);
            asm volatile("s_waitcnt vmcnt(0)" ::: "memory");  // exports drained
            __syncthreads();   // sync3: exports + X(t+1) staged
            if (tid == 0)
                __hip_atomic_fetch_add(myfl, 1u, __ATOMIC_RELAXED,
                                       __HIP_MEMORY_SCOPE_SYSTEM);
        }
    }
}

extern "C" void kernel_launch(void* const* d_in, const int* in_sizes, int n_in,
                              void* d_out, int out_size, void* d_ws, size_t ws_size,
                              hipStream_t stream)
{
    const float* x    = (const float*)d_in[0];
    const int*   lbl  = (const int*)  d_in[1];
    const float* kern = (const float*)d_in[2];
    const float* rk   = (const float*)d_in[3];
    const float* bias = (const float*)d_in[4];
    float* out = (float*)d_out;

    // ws: xb 20.97MB | hb0 4.19 | hb1 4.19 | wt_in 0.147 | wt_rk 1.18 | flags 2KB
    u16* xb    = (u16*)d_ws;
    u16* hb0   = xb + 10485760;
    u16* hb1   = hb0 + 2097152;
    u16* wt_in = hb1 + 2097152;
    u16* wt_rk = wt_in + 73728;
    unsigned* flags = (unsigned*)(wt_rk + 589824);

    hipLaunchKernelGGL(prep_x, dim3(2048), dim3(256), 0, stream, x, xb);
    hipLaunchKernelGGL(prep_w, dim3(324), dim3(256), 0, stream,
                       kern, rk, wt_in, wt_rk, flags);

    // Regular launch; co-residency guaranteed by __launch_bounds__(256, 2)
    // capacity (2 blocks/CU x 256 CUs = 512 blocks exactly; guide §1).
    hipLaunchKernelGGL(lstm_all, dim3(512), dim3(256), 0, stream,
                       xb, wt_in, wt_rk, bias, lbl, hb0, hb1, out, flags);
}

// Round 22
// 172.098 us; speedup vs baseline: 2.6321x; 1.4030x over previous
//
#include <hip/hip_runtime.h>

// ConvLSTM2D MI355X, R22: R17 anchor (176us) + ONE change: prep_x dispatch
// removed; X halos staged from f32 with in-register f2bf (R13-proven pattern).
// R21's second change (deferred ring import) is dead: inline-asm load results
// held across 144 MFMAs get copied/spilled by regalloc before the load lands
// (SIInsertWaitcnts can't track asm-internal VMEM defs) -> garbage. Import
// stays in R17's tight load->waitcnt window form.
// 512 blocks x 256 thr (2 independent blocks/CU), local 8-neighbor flag sync,
// h interior in LDS, ring via sc0sc1 16B, c in registers, X-before-poll.

typedef __attribute__((ext_vector_type(8))) short short8v;
typedef __attribute__((ext_vector_type(4))) float f32x4;
typedef __attribute__((ext_vector_type(4))) unsigned int u32x4;
typedef unsigned short u16;

#define HS 808             // shorts per kb block in H halo (101 x 16B slots)
#define HB 3200            // H halo base (shorts); X halo = [0, 3200)

__device__ __forceinline__ u16 f2bf(float x) {
    union { float f; unsigned u; } a; a.f = x;
    unsigned r = a.u + 0x7FFFu + ((a.u >> 16) & 1u);   // RNE
    return (u16)(r >> 16);
}
__device__ __forceinline__ float sigf(float x) { return 1.0f / (1.0f + __expf(-x)); }
__device__ __forceinline__ float tanhf_(float x) {
    float e = __expf(2.0f * x);
    return 1.0f - 2.0f / (e + 1.0f);
}

// ---- prep: weights -> staged layout + zero flags ----
__global__ __launch_bounds__(256)
void prep_w(const float* __restrict__ kern, const float* __restrict__ rk,
            u16* __restrict__ wt_in, u16* __restrict__ wt_rk,
            unsigned* __restrict__ flags) {
    int idx = blockIdx.x * 256 + threadIdx.x;
    if (idx < 512) flags[idx] = 0u;
    if (idx >= 82944) return;
    const float* s;
    u16* dst;
    if (idx < 9216) {
        int co = idx & 255, ckb = idx >> 8;          // 0..35 = tap*4+kb
        int tap = ckb >> 2, kb = ckb & 3;
        s = kern + (size_t)((tap << 5) + (kb << 3)) * 256 + co;
        dst = wt_in + (size_t)idx * 8;
    } else {
        int j = idx - 9216;
        int co = j & 255, rest = j >> 8;             // 0..287
        int kb = rest & 3, gc = rest >> 2;           // gc = g*18 + cc
        int g = gc / 18, cc = gc - g * 18;
        int tap = cc >> 1;
        int cib = (cc & 1) << 5;
        s = rk + (size_t)(((g * 9 + tap) << 6) + cib + (kb << 3)) * 256 + co;
        dst = wt_rk + (size_t)j * 8;
    }
    union { u16 u[8]; uint4 q; } o;
    #pragma unroll
    for (int i = 0; i < 8; ++i) o.u[i] = f2bf(s[i * 256]);
    *(uint4*)dst = o.q;
}

// stage X halo from f32 with in-register convert (no prep_x pass; R13 pattern)
__device__ __forceinline__ void stageXf(const float* __restrict__ src,
                                        short* __restrict__ halX,
                                        int tid, int y0, int x0) {
    #pragma unroll 2
    for (int s = tid; s < 400; s += 256) {
        int pos = s >> 2, kb = s & 3;
        int hy = pos / 10, hx = pos - hy * 10;
        int gy = y0 + hy - 1, gx = x0 + hx - 1;
        union { u16 u[8]; short8v v; } o;
        o.v = (short8v){0,0,0,0,0,0,0,0};
        if ((unsigned)gy < 64u && (unsigned)gx < 64u) {
            const float* p = src + (((gy << 6) + gx) << 5) + (kb << 3);
            float4 a0 = *(const float4*)p;
            float4 a1 = *(const float4*)(p + 4);
            o.u[0] = f2bf(a0.x); o.u[1] = f2bf(a0.y);
            o.u[2] = f2bf(a0.z); o.u[3] = f2bf(a0.w);
            o.u[4] = f2bf(a1.x); o.u[5] = f2bf(a1.y);
            o.u[6] = f2bf(a1.z); o.u[7] = f2bf(a1.w);
        }
        *(short8v*)&halX[kb * 800 + pos * 8] = o.v;
    }
}

// ---- persistent fused conv + gates, all timesteps ----
__global__ __launch_bounds__(256, 2)
void lstm_all(const float* __restrict__ xf,   // (8,10,64,64,32) f32
              const u16* __restrict__ wt_in, const u16* __restrict__ wt_rk,
              const float* __restrict__ bias, const int* __restrict__ labels,
              u16* __restrict__ hb0, u16* __restrict__ hb1,  // h ring bufs
              float* __restrict__ out, unsigned* __restrict__ flags)
{
    // X halo @0: [kb4][100][8] (3200 shorts); H halo @3200: [kb8][HS=808]
    __shared__ short hal[HB + 8 * HS];   // 9664 shorts = 19,328 B

    const int tid  = threadIdx.x;
    const int lane = tid & 63;
    const int wq   = tid >> 6;                 // wave = f-slice 0..3
    const int b    = blockIdx.x >> 6;
    const int tile = blockIdx.x & 63;
    const int ty = tile >> 3, tx = tile & 7;
    const int y0 = ty << 3, x0 = tx << 3;
    const int g = labels[b];

    const int co_l = lane & 15;
    const int kbl  = lane >> 4;
    const int prow = (lane & 15) >> 3, pcol = lane & 7;
    const int f = (wq << 4) + co_l;

    float bv[4];
    #pragma unroll
    for (int n = 0; n < 4; ++n)
        bv[n] = bias[(g << 8) + (n << 6) + f];

    int aoffm[4];
    #pragma unroll
    for (int m = 0; m < 4; ++m)
        aoffm[m] = ((m << 1) + prow) * 10 + pcol;

    int poff[4][4], loff[4][4];
    #pragma unroll
    for (int m = 0; m < 4; ++m)
        #pragma unroll
        for (int rr = 0; rr < 4; ++rr) {
            int pf = (kbl << 2) + rr;
            int ly = (m << 1) + (pf >> 3);
            int lx = pf & 7;
            poff[m][rr] = ((((y0 + ly) << 6) + x0 + lx) << 6) + f;
            loff[m][rr] = HB + (f >> 3) * HS + ((ly + 1) * 10 + lx + 1) * 8 + (f & 7);
        }

    float cst[4][4];
    #pragma unroll
    for (int m = 0; m < 4; ++m)
        #pragma unroll
        for (int rr = 0; rr < 4; ++rr) cst[m][rr] = 0.0f;

    const float* xsrc = xf + ((size_t)b * 10 << 17);
    float*       ob0  = out + ((size_t)b * 10 << 18);
    unsigned*    myfl = flags + (b << 6) + tile;

    // zero H halo (out-of-image ring cells stay 0 forever); stage X(0)
    for (int s = tid; s < 808; s += 256)
        *(short8v*)&hal[HB + s * 8] = (short8v){0,0,0,0,0,0,0,0};
    stageXf(xsrc, hal, tid, y0, x0);
    __syncthreads();

    for (int t = 0; t < 10; ++t) {
        u16* hw = ((t & 1) ? hb1 : hb0) + ((size_t)b << 18);   // h(t)

        f32x4 acc[4][4];
        #pragma unroll
        for (int n = 0; n < 4; ++n)
            #pragma unroll
            for (int m = 0; m < 4; ++m)
                acc[m][n] = (f32x4){bv[n], bv[n], bv[n], bv[n]};

        // ---- phase X: 9 chunks (h-independent) ----
        #pragma unroll 3
        for (int tap = 0; tap < 9; ++tap) {
            const int koff = (tap / 3) * 10 + (tap % 3);
            const u16* wb = wt_in + (size_t)((((tap << 2) + kbl) << 8) + f) * 8;
            short8v bfr[4], af[4];
            #pragma unroll
            for (int n = 0; n < 4; ++n)
                bfr[n] = *(const short8v*)&wb[(size_t)n << 9];
            #pragma unroll
            for (int m = 0; m < 4; ++m)
                af[m] = *(const short8v*)&hal[kbl * 800 + (aoffm[m] + koff) * 8];
            #pragma unroll
            for (int m = 0; m < 4; ++m)
                #pragma unroll
                for (int n = 0; n < 4; ++n)
                    acc[m][n] = __builtin_amdgcn_mfma_f32_16x16x32_bf16(af[m], bfr[n], acc[m][n], 0, 0, 0);
        }

        if (t > 0) {
            // ---- poll 8 neighbor flags (wave 0): need h(t-1) exported ----
            if (tid < 64) {
                bool valid = false; int fidx = 0;
                if (tid < 8) {
                    int kk = tid + (tid >= 4);       // 0..8 skipping center
                    int nty = ty + kk / 3 - 1, ntx = tx + kk % 3 - 1;
                    valid = (unsigned)nty < 8u && (unsigned)ntx < 8u;
                    fidx = (b << 6) + (nty << 3) + ntx;
                }
                unsigned tgt = (unsigned)t;
                int guard = 0;
                for (;;) {
                    unsigned vv = tgt;
                    if (valid)
                        vv = __hip_atomic_load(flags + fidx, __ATOMIC_RELAXED,
                                               __HIP_MEMORY_SCOPE_SYSTEM);
                    if (__all(vv >= tgt)) break;
                    if (++guard > (1 << 19)) break;
                    __builtin_amdgcn_s_sleep(2);
                }
            }
            __syncthreads();   // neighbors' h(t-1) rings globally visible

            // ---- import ring h(t-1): 36 px x 8 units, sc0sc1 16B ----
            {
                const u16* hr = ((t & 1) ? hb0 : hb1) + ((size_t)b << 18);
                #pragma unroll
                for (int u = 0; u < 2; ++u) {
                    int s = tid + (u << 8);
                    if (s < 288) {
                        int posr = s >> 3, kb = s & 7;
                        int hy, hx;
                        if (posr < 10)      { hy = 0; hx = posr; }
                        else if (posr < 20) { hy = 9; hx = posr - 10; }
                        else { int v = posr - 20; hy = 1 + (v >> 1); hx = (v & 1) * 9; }
                        int gy = y0 + hy - 1, gx = x0 + hx - 1;
                        bool inb = (unsigned)gy < 64u && (unsigned)gx < 64u;
                        const u16* ga = inb ? (hr + (((gy << 6) + gx) << 6) + (kb << 3)) : hr;
                        u32x4 v;
                        asm volatile("global_load_dwordx4 %0, %1, off sc0 sc1"
                                     : "=v"(v) : "v"(ga) : "memory");
                        asm volatile("s_waitcnt vmcnt(0)" ::: "memory");
                        __builtin_amdgcn_sched_barrier(0);
                        if (!inb) v = (u32x4){0u, 0u, 0u, 0u};
                        *(u32x4*)&hal[HB + kb * HS + (hy * 10 + hx) * 8] = v;
                    }
                }
            }
            __syncthreads();   // ring in LDS

            // ---- phase H: 18 chunks ----
            #pragma unroll 3
            for (int c = 0; c < 18; ++c) {
                const int tap = c >> 1;
                const int koff = (tap / 3) * 10 + (tap % 3);
                const u16* wb = wt_rk + (size_t)(((((g * 18 + c) << 2) + kbl) << 8) + f) * 8;
                short8v bfr[4], af[4];
                #pragma unroll
                for (int n = 0; n < 4; ++n)
                    bfr[n] = *(const short8v*)&wb[(size_t)n << 9];
                const int abase = HB + (((c & 1) << 2) + kbl) * HS;
                #pragma unroll
                for (int m = 0; m < 4; ++m)
                    af[m] = *(const short8v*)&hal[abase + (aoffm[m] + koff) * 8];
                #pragma unroll
                for (int m = 0; m < 4; ++m)
                    #pragma unroll
                    for (int n = 0; n < 4; ++n)
                        acc[m][n] = __builtin_amdgcn_mfma_f32_16x16x32_bf16(af[m], bfr[n], acc[m][n], 0, 0, 0);
            }
        }
        __syncthreads();   // sync1: H-LDS (h(t-1)) reads complete

        // ---- gates + out store + h(t) interior -> LDS ----
        float* ob = ob0 + ((size_t)t << 18);
        #pragma unroll
        for (int m = 0; m < 4; ++m) {
            #pragma unroll
            for (int rr = 0; rr < 4; ++rr) {
                float zi = acc[m][0][rr], zf = acc[m][1][rr];
                float zg = acc[m][2][rr], zo = acc[m][3][rr];
                float cn = sigf(zf) * cst[m][rr] + sigf(zi) * tanhf_(zg);
                float hn = sigf(zo) * tanhf_(cn);
                cst[m][rr] = cn;
                ob[poff[m][rr]] = hn;
                hal[loff[m][rr]] = (short)f2bf(hn);
            }
        }
        __syncthreads();   // sync2: interior h(t) in LDS

        if (t < 9) {
            // ---- ring export: 28 boundary px x 8 units, sc0sc1 16B ----
            if (tid < 224) {
                int pxr = tid >> 3, kb = tid & 7;
                int dy, dx;
                if (pxr < 8)       { dy = 0; dx = pxr; }
                else if (pxr < 16) { dy = 7; dx = pxr - 8; }
                else { int v = pxr - 16; dy = 1 + (v >> 1); dx = (v & 1) * 7; }
                u32x4 v = *(const u32x4*)&hal[HB + kb * HS + ((dy + 1) * 10 + dx + 1) * 8];
                const u16* ga = hw + ((((y0 + dy) << 6) + x0 + dx) << 6) + (kb << 3);
                asm volatile("global_store_dwordx4 %0, %1, off sc0 sc1"
                             :: "v"(ga), "v"(v) : "memory");
            }
            // ---- stage X(t+1) from f32 (overlaps export latency) ----
            stageXf(xsrc + ((size_t)(t + 1) << 17), hal, tid, y0, x0);
            asm volatile("s_waitcnt vmcnt(0)" ::: "memory");  // exports drained
            __syncthreads();   // sync3: exports + X(t+1) staged
            if (tid == 0)
                __hip_atomic_fetch_add(myfl, 1u, __ATOMIC_RELAXED,
                                       __HIP_MEMORY_SCOPE_SYSTEM);
        }
    }
}

extern "C" void kernel_launch(void* const* d_in, const int* in_sizes, int n_in,
                              void* d_out, int out_size, void* d_ws, size_t ws_size,
                              hipStream_t stream)
{
    const float* x    = (const float*)d_in[0];
    const int*   lbl  = (const int*)  d_in[1];
    const float* kern = (const float*)d_in[2];
    const float* rk   = (const float*)d_in[3];
    const float* bias = (const float*)d_in[4];
    float* out = (float*)d_out;

    // ws: hb0 4.19MB | hb1 4.19MB | wt_in 0.147 | wt_rk 1.18 | flags 2KB
    u16* hb0   = (u16*)d_ws;
    u16* hb1   = hb0 + 2097152;
    u16* wt_in = hb1 + 2097152;
    u16* wt_rk = wt_in + 73728;
    unsigned* flags = (unsigned*)(wt_rk + 589824);

    hipLaunchKernelGGL(prep_w, dim3(324), dim3(256), 0, stream,
                       kern, rk, wt_in, wt_rk, flags);

    // Regular launch; co-residency guaranteed by __launch_bounds__(256, 2)
    // capacity (2 blocks/CU x 256 CUs = 512 blocks exactly; guide §1).
    hipLaunchKernelGGL(lstm_all, dim3(512), dim3(256), 0, stream,
                       x, wt_in, wt_rk, bias, lbl, hb0, hb1, out, flags);
}